// Round 17
// baseline (159.982 us; speedup 1.0000x reference)
//
#include <hip/hip_runtime.h>
#include <hip/hip_fp16.h>

#define SDIM 48
#define SP   110592           // 48^3
#define C_IN 16
#define O_OUT 32
#define T27  27
#define OST  96               // offs row stride (channel-last, 81 used, 96 padded)
#define OLROW 100             // offset-LDS row stride (ush) -> conflict-free

typedef __attribute__((ext_vector_type(8))) _Float16 f16x8;
typedef __attribute__((ext_vector_type(4))) float f32x4;

__device__ __forceinline__ float h2f(unsigned short u) {
    return __half2float(__builtin_bit_cast(__half, u));
}
__device__ __forceinline__ unsigned short f2h(float f) {
    __half h = __float2half(f);            // RNE
    return __builtin_bit_cast(unsigned short, h);
}

// ---------- Kernel 0a: x [n][c][sp] fp32 -> xT [n][sp][c] f16 ----------------
__global__ __launch_bounds__(256)
void prep_xT(const float* __restrict__ x, unsigned short* __restrict__ xT) {
    __shared__ float l[256 * 17];
    const int tid = threadIdx.x;
    const int b   = blockIdx.x;          // 0..863
    const int n   = b / 432;
    const int sp0 = (b - n * 432) * 256;
    #pragma unroll
    for (int c = 0; c < 16; ++c)
        l[tid * 17 + c] = x[((size_t)(n * 16 + c)) * SP + sp0 + tid];
    __syncthreads();
    unsigned int u[8];
    #pragma unroll
    for (int q = 0; q < 8; ++q) {
        unsigned short a  = f2h(l[tid * 17 + 2 * q]);
        unsigned short bb = f2h(l[tid * 17 + 2 * q + 1]);
        u[q] = (unsigned int)a | ((unsigned int)bb << 16);
    }
    uint4* dst = (uint4*)(xT + ((size_t)(n * SP + sp0 + tid)) * 16);
    dst[0] = make_uint4(u[0], u[1], u[2], u[3]);
    dst[1] = make_uint4(u[4], u[5], u[6], u[7]);
}

// ---------- Kernel 0b: pack offset-conv weights into B-fragment layout (f16) -
__global__ __launch_bounds__(256)
void prep_bfrag(const float* __restrict__ ow, unsigned short* __restrict__ Bf) {
    int idx = blockIdx.x * 256 + threadIdx.x;     // 0..43007
    int r    = idx & 7;
    int lane = (idx >> 3) & 63;
    int snt  = idx >> 9;                          // s*6+nt, 0..83
    int s = snt / 6, nt = snt - s * 6;
    int kk  = ((lane >> 4) << 3) + r;
    int g   = nt * 16 + (lane & 15);
    int tap = 2 * s + (kk >> 4);
    int c   = kk & 15;
    float v = 0.f;
    if (tap < 27 && g < 81) v = ow[((size_t)(g * 16 + c)) * 27 + tap];
    Bf[idx] = f2h(v);
}

// ---------- Kernel 0c: pack einsum weights into B-frag layout (14 k-steps) ---
__global__ __launch_bounds__(256)
void prep_wfrag(const float* __restrict__ w, unsigned short* __restrict__ Wf) {
    int idx = blockIdx.x * 256 + threadIdx.x;     // 0..14335
    int r    = idx & 7;
    int lane = (idx >> 3) & 63;
    int snt  = idx >> 9;                          // s*2+nt, 0..27
    int s = snt >> 1, nt = snt & 1;
    int kk  = ((lane >> 4) << 3) + r;
    int o   = nt * 16 + (lane & 15);
    int tap = 2 * s + (kk >> 4);
    int c   = kk & 15;
    float v = 0.f;
    if (tap < 27) v = w[((size_t)(o * 16 + c)) * 27 + tap];
    Wf[idx] = f2h(v);
}

// ---------- Kernel 1: offset conv as implicit-GEMM MFMA (f16) ----------------
// Output: offs[n][sp][96] f16 channel-last, contiguous 12KB tile store.
__global__ __launch_bounds__(256)
void offs_conv_mfma(const unsigned short* __restrict__ xT,
                    const unsigned short* __restrict__ Bf,
                    const float* __restrict__ ob,
                    unsigned short* __restrict__ offs) {
    __shared__ unsigned short Alds[256 * 8];      // 4KB staging
    __shared__ unsigned short Tl[64 * 104];       // 13KB epilogue transpose
    const int tid  = threadIdx.x;
    const int lane = tid & 63;
    const int wid  = tid >> 6;
    // XCD-aware chunked swizzle: 3456 = 8 x 432
    const int bid  = (blockIdx.x & 7) * 432 + (blockIdx.x >> 3);
    const int m    = tid & 63;
    const int n    = (bid >= 1728) ? 1 : 0;
    const int sp   = bid * 64 + m - n * SP;
    const int z    = sp / 2304;
    const int rem  = sp - z * 2304;
    const int y    = rem / 48;
    const int xx   = rem - y * 48;
    const int tapoff = wid >> 1;
    const int half   = wid & 1;

    auto stage_load = [&](int s) -> uint4 {
        int tap = 2 * s + tapoff;
        int kd = tap / 9;
        int t2 = tap - kd * 9;
        int kh = t2 / 3;
        int kw = t2 - kh * 3;
        int di = z + kd - 1, hi = y + kh - 1, wi = xx + kw - 1;
        bool ok = (tap < 27) && ((unsigned)di < 48u) && ((unsigned)hi < 48u) &&
                  ((unsigned)wi < 48u);
        uint4 v = make_uint4(0u, 0u, 0u, 0u);
        if (ok) {
            size_t off = ((size_t)(n * SP + (di * 2304 + hi * 48 + wi))) * 16 + half * 8;
            v = *(const uint4*)(xT + off);
        }
        return v;
    };

    f32x4 acc[6];
    #pragma unroll
    for (int t = 0; t < 6; ++t) acc[t] = (f32x4){0.f, 0.f, 0.f, 0.f};

    uint4 v = stage_load(0);
    for (int s = 0; s < 14; ++s) {
        __syncthreads();
        *(uint4*)&Alds[tid * 8] = v;
        __syncthreads();
        if (s < 13) v = stage_load(s + 1);        // prefetch overlaps MFMA
        f16x8 a = *(const f16x8*)&Alds[(((lane >> 4) * 64) + (wid * 16) + (lane & 15)) * 8];
        const f16x8* bp = (const f16x8*)Bf + (size_t)(s * 6) * 64 + lane;
        #pragma unroll
        for (int nt = 0; nt < 6; ++nt) {
            f16x8 b = bp[nt * 64];
            acc[nt] = __builtin_amdgcn_mfma_f32_16x16x32_f16(a, b, acc[nt], 0, 0, 0);
        }
    }

    // epilogue: bias + f16 into LDS [row][g] (stride 104), then contiguous out
    const int mrow = wid * 16 + ((lane >> 4) << 2);
    #pragma unroll
    for (int nt = 0; nt < 6; ++nt) {
        int g = nt * 16 + (lane & 15);
        float bia = (g < 81) ? ob[g] : 0.f;
        #pragma unroll
        for (int r = 0; r < 4; ++r)
            Tl[(mrow + r) * 104 + g] = f2h(acc[nt][r] + bia);
    }
    __syncthreads();
    unsigned short* dst = offs + (size_t)bid * (64 * OST);
    #pragma unroll
    for (int k = 0; k < 3; ++k) {
        int idx = k * 256 + tid;                  // 0..767 uint4-chunks
        int row = idx / 12;
        int col = (idx - row * 12) * 8;
        uint4 vv = *(const uint4*)&Tl[row * 104 + col];
        *(uint4*)(dst + row * OST + col) = vv;
    }
}

// ---------- Kernel 2: pipelined full-K-per-wave fused sampling ---------------
// 256 threads = 4 waves x 16 points = 64 points/block (3456 blocks, finer
// scheduling granularity vs R16's 512-thread blocks -> smaller drain tail).
// Explicit 2-deep software pipeline: stage(s+1) computes position math and
// ISSUES all 8 gathers before the interp+MFMA of step s consumes stage(s)'s
// data -> gather latency hides inside the wave (counted vmcnt), independent
// of occupancy. tap==27 pad handled branchlessly (valid-mask on wd0/wd1;
// offs pad cols are written as zeros by kernel 1).
// REGISTER-CAP HISTORY (do not tighten): cap<=64 on this sampler spills
// (R5: FETCH x7, R9: WRITE x5). (256,4) -> cap 128; pipeline peak ~118 VGPR.
__global__ __launch_bounds__(256, 4)
void deform_fused(const unsigned short* __restrict__ xT,
                  const unsigned short* __restrict__ Wf,
                  const unsigned short* __restrict__ offs,
                  float* __restrict__ out) {
    __shared__ unsigned short OLDS[64 * OLROW];   // 12.8KB offsets

    const int tid  = threadIdx.x;
    const int lane = tid & 63;
    const int wv   = tid >> 6;                    // wave 0..3
    const int pl   = lane & 15;                   // point-local (A-frag row)
    const int chh  = (lane >> 4) & 1;             // channel half
    const int tl   = lane >> 5;                   // tap-local in k-step
    // XCD-aware chunked swizzle: 3456 = 8 x 432
    const int bid  = (blockIdx.x & 7) * 432 + (blockIdx.x >> 3);
    const int n    = (bid >= 1728) ? 1 : 0;
    const int sp0  = bid * 64 - n * SP;

    // ---- phase 0: coalesced offset preload (64 rows x 96 ush = 768 uint4) --
    #pragma unroll
    for (int k = 0; k < 3; ++k) {
        int idx = k * 256 + tid;
        int row = idx / 12;
        int col = (idx - row * 12) * 8;
        uint4 v = *(const uint4*)(offs + ((size_t)(n * SP + sp0 + row)) * OST + col);
        *(uint4*)&OLDS[row * OLROW + col] = v;
    }
    __syncthreads();

    const uint4* xq4 = (const uint4*)(xT + (size_t)n * SP * 16);

    const int p  = wv * 16 + pl;                  // point 0..63
    const int sp = sp0 + p;
    const int z  = sp / 2304;
    const int rm = sp - z * 2304;
    const int y  = rm / 48;
    const int xx = rm - y * 48;

    // stage(s): position math + weights + ISSUE 8 gathers for k-step s.
    auto stage = [&](int s, uint4* cv, float* cw) {
        const int tap = 2 * s + tl;               // 0..27 (27 = masked pad)
        const int kd = tap / 9;
        const int t2 = tap - kd * 9;
        const int kh = t2 / 3;
        const int kw = t2 - kh * 3;
        // LDS reads in-bounds for tap=27 (cols 27/54/81 <= 95); pad cols = 0
        float pd = (float)(z + kd - 1)  + h2f(OLDS[p * OLROW + tap]);
        float ph = (float)(y + kh - 1)  + h2f(OLDS[p * OLROW + 27 + tap]);
        float pw = (float)(xx + kw - 1) + h2f(OLDS[p * OLROW + 54 + tap]);
        float df = floorf(pd), hf = floorf(ph), wf = floorf(pw);
        float fd = pd - df, fh = ph - hf, fw = pw - wf;
        int d0 = (int)df, h0 = (int)hf, w0 = (int)wf;
        const float valid = (tap < 27) ? 1.f : 0.f;
        float wd0 = (((unsigned)d0       < 48u) ? (1.f - fd) : 0.f) * valid;
        float wd1 = (((unsigned)(d0 + 1) < 48u) ? fd : 0.f) * valid;
        float wh0 = ((unsigned)h0       < 48u) ? (1.f - fh) : 0.f;
        float wh1 = ((unsigned)(h0 + 1) < 48u) ? fh : 0.f;
        float ww0 = ((unsigned)w0       < 48u) ? (1.f - fw) : 0.f;
        float ww1 = ((unsigned)(w0 + 1) < 48u) ? fw : 0.f;
        int dc0 = min(max(d0,     0), 47) * 2304;
        int dc1 = min(max(d0 + 1, 0), 47) * 2304;
        int hc0 = min(max(h0,     0), 47) * 48;
        int hc1 = min(max(h0 + 1, 0), 47) * 48;
        int wc0 = min(max(w0,     0), 47);
        int wc1 = min(max(w0 + 1, 0), 47);

        float wdh[4] = {wd0 * wh0, wd0 * wh1, wd1 * wh0, wd1 * wh1};
        int   rdh[4] = {dc0 + hc0, dc0 + hc1, dc1 + hc0, dc1 + hc1};

        #pragma unroll
        for (int jj = 0; jj < 8; ++jj) {
            int dh = jj >> 1;
            int ws = jj & 1;
            int idx = rdh[dh] + (ws ? wc1 : wc0);
            cv[jj] = xq4[(size_t)idx * 2 + chh];
            cw[jj] = wdh[dh] * (ws ? ww1 : ww0);
        }
    };

    f32x4 acc0 = (f32x4){0.f, 0.f, 0.f, 0.f};
    f32x4 acc1 = (f32x4){0.f, 0.f, 0.f, 0.f};

    uint4 cvA[8];
    float cwA[8];
    stage(0, cvA, cwA);

    #pragma unroll
    for (int s = 0; s < 14; ++s) {
        uint4 cvB[8];
        float cwB[8];
        if (s < 13) stage(s + 1, cvB, cwB);       // next-step gathers in flight

        // packed-f16 interp on stage(s) data: acc IS the A-fragment
        const __half2 z2 = __builtin_bit_cast(__half2, (unsigned int)0);
        __half2 s2[4] = {z2, z2, z2, z2};
        #pragma unroll
        for (int jj = 0; jj < 8; ++jj) {
            unsigned int wp;
            asm("v_cvt_pkrtz_f16_f32 %0, %1, %2" : "=v"(wp) : "v"(cwA[jj]), "v"(cwA[jj]));
            __half2 wh = __builtin_bit_cast(__half2, wp);
            unsigned int uu[4] = {cvA[jj].x, cvA[jj].y, cvA[jj].z, cvA[jj].w};
            #pragma unroll
            for (int q = 0; q < 4; ++q)
                s2[q] = __hfma2(__builtin_bit_cast(__half2, uu[q]), wh, s2[q]);
        }
        uint4 au = make_uint4(__builtin_bit_cast(unsigned int, s2[0]),
                              __builtin_bit_cast(unsigned int, s2[1]),
                              __builtin_bit_cast(unsigned int, s2[2]),
                              __builtin_bit_cast(unsigned int, s2[3]));
        f16x8 a = __builtin_bit_cast(f16x8, au);
        const f16x8* bp = (const f16x8*)Wf + (size_t)(s * 2) * 64 + lane;
        acc0 = __builtin_amdgcn_mfma_f32_16x16x32_f16(a, bp[0],  acc0, 0, 0, 0);
        acc1 = __builtin_amdgcn_mfma_f32_16x16x32_f16(a, bp[64], acc1, 0, 0, 0);

        // rotate pipeline registers (renamed away by full unroll)
        #pragma unroll
        for (int jj = 0; jj < 8; ++jj) {
            cvA[jj] = cvB[jj];
            cwA[jj] = cwB[jj];
        }
    }

    // ---- epilogue: direct float4 stores (rows 4q..4q+3 = consecutive sp) ----
    {
        const int o   = lane & 15;
        const int row = (lane >> 4) << 2;         // 0,4,8,12
        float* op0 = out + ((size_t)(n * O_OUT + o))      * SP + sp0 + wv * 16 + row;
        float* op1 = out + ((size_t)(n * O_OUT + 16 + o)) * SP + sp0 + wv * 16 + row;
        *(float4*)op0 = make_float4(acc0[0], acc0[1], acc0[2], acc0[3]);
        *(float4*)op1 = make_float4(acc1[0], acc1[1], acc1[2], acc1[3]);
    }
}

// -----------------------------------------------------------------------------
extern "C" void kernel_launch(void* const* d_in, const int* in_sizes, int n_in,
                              void* d_out, int out_size, void* d_ws, size_t ws_size,
                              hipStream_t stream) {
    (void)in_sizes; (void)n_in; (void)out_size; (void)ws_size;
    const float* x      = (const float*)d_in[0];
    const float* weight = (const float*)d_in[1];
    const float* ow     = (const float*)d_in[2];
    const float* ob     = (const float*)d_in[3];
    float* out = (float*)d_out;

    unsigned short* offs_b = (unsigned short*)d_ws;            // 2*SP*96 f16 = 42.5MB
    unsigned short* xT     = offs_b + (size_t)2 * SP * OST;    // 2*SP*16 f16 = 7.1MB
    unsigned short* Bf     = xT + (size_t)2 * SP * 16;         // 43008 f16
    unsigned short* Wf     = Bf + 43008;                       // 14336 f16

    prep_xT<<<864, 256, 0, stream>>>(x, xT);
    prep_bfrag<<<168, 256, 0, stream>>>(ow, Bf);
    prep_wfrag<<<56, 256, 0, stream>>>(weight, Wf);
    offs_conv_mfma<<<3456, 256, 0, stream>>>(xT, Bf, ob, offs_b);
    deform_fused<<<3456, 256, 0, stream>>>(xT, Wf, offs_b, out);
}

// Round 20
// 158.746 us; speedup vs baseline: 1.0078x; 1.0078x over previous
//
#include <hip/hip_runtime.h>
#include <hip/hip_fp16.h>

#define SDIM 48
#define SP   110592           // 48^3
#define C_IN 16
#define O_OUT 32
#define T27  27
#define OST  96               // offs row stride (channel-last, 81 used, 96 padded)
#define OLROW 100             // offset-LDS row stride (ush) -> conflict-free

typedef __attribute__((ext_vector_type(8))) _Float16 f16x8;
typedef __attribute__((ext_vector_type(4))) float f32x4;

__device__ __forceinline__ float h2f(unsigned short u) {
    return __half2float(__builtin_bit_cast(__half, u));
}
__device__ __forceinline__ unsigned short f2h(float f) {
    __half h = __float2half(f);            // RNE
    return __builtin_bit_cast(unsigned short, h);
}

// ---------- Kernel 0a: x [n][c][sp] fp32 -> xT [n][sp][c] f16 ----------------
__global__ __launch_bounds__(256)
void prep_xT(const float* __restrict__ x, unsigned short* __restrict__ xT) {
    __shared__ float l[256 * 17];
    const int tid = threadIdx.x;
    const int b   = blockIdx.x;          // 0..863
    const int n   = b / 432;
    const int sp0 = (b - n * 432) * 256;
    #pragma unroll
    for (int c = 0; c < 16; ++c)
        l[tid * 17 + c] = x[((size_t)(n * 16 + c)) * SP + sp0 + tid];
    __syncthreads();
    unsigned int u[8];
    #pragma unroll
    for (int q = 0; q < 8; ++q) {
        unsigned short a  = f2h(l[tid * 17 + 2 * q]);
        unsigned short bb = f2h(l[tid * 17 + 2 * q + 1]);
        u[q] = (unsigned int)a | ((unsigned int)bb << 16);
    }
    uint4* dst = (uint4*)(xT + ((size_t)(n * SP + sp0 + tid)) * 16);
    dst[0] = make_uint4(u[0], u[1], u[2], u[3]);
    dst[1] = make_uint4(u[4], u[5], u[6], u[7]);
}

// ---------- Kernel 0b: pack offset-conv weights into B-fragment layout (f16) -
__global__ __launch_bounds__(256)
void prep_bfrag(const float* __restrict__ ow, unsigned short* __restrict__ Bf) {
    int idx = blockIdx.x * 256 + threadIdx.x;     // 0..43007
    int r    = idx & 7;
    int lane = (idx >> 3) & 63;
    int snt  = idx >> 9;                          // s*6+nt, 0..83
    int s = snt / 6, nt = snt - s * 6;
    int kk  = ((lane >> 4) << 3) + r;
    int g   = nt * 16 + (lane & 15);
    int tap = 2 * s + (kk >> 4);
    int c   = kk & 15;
    float v = 0.f;
    if (tap < 27 && g < 81) v = ow[((size_t)(g * 16 + c)) * 27 + tap];
    Bf[idx] = f2h(v);
}

// ---------- Kernel 0c: pack einsum weights into B-frag layout (14 k-steps) ---
__global__ __launch_bounds__(256)
void prep_wfrag(const float* __restrict__ w, unsigned short* __restrict__ Wf) {
    int idx = blockIdx.x * 256 + threadIdx.x;     // 0..14335
    int r    = idx & 7;
    int lane = (idx >> 3) & 63;
    int snt  = idx >> 9;                          // s*2+nt, 0..27
    int s = snt >> 1, nt = snt & 1;
    int kk  = ((lane >> 4) << 3) + r;
    int o   = nt * 16 + (lane & 15);
    int tap = 2 * s + (kk >> 4);
    int c   = kk & 15;
    float v = 0.f;
    if (tap < 27) v = w[((size_t)(o * 16 + c)) * 27 + tap];
    Wf[idx] = f2h(v);
}

// ---------- Kernel 1: offset conv as implicit-GEMM MFMA (f16) ----------------
// Output: offs[n][sp][96] f16 channel-last, contiguous 12KB tile store.
__global__ __launch_bounds__(256)
void offs_conv_mfma(const unsigned short* __restrict__ xT,
                    const unsigned short* __restrict__ Bf,
                    const float* __restrict__ ob,
                    unsigned short* __restrict__ offs) {
    __shared__ unsigned short Alds[256 * 8];      // 4KB staging
    __shared__ unsigned short Tl[64 * 104];       // 13KB epilogue transpose
    const int tid  = threadIdx.x;
    const int lane = tid & 63;
    const int wid  = tid >> 6;
    // XCD-aware chunked swizzle: 3456 = 8 x 432
    const int bid  = (blockIdx.x & 7) * 432 + (blockIdx.x >> 3);
    const int m    = tid & 63;
    const int n    = (bid >= 1728) ? 1 : 0;
    const int sp   = bid * 64 + m - n * SP;
    const int z    = sp / 2304;
    const int rem  = sp - z * 2304;
    const int y    = rem / 48;
    const int xx   = rem - y * 48;
    const int tapoff = wid >> 1;
    const int half   = wid & 1;

    auto stage_load = [&](int s) -> uint4 {
        int tap = 2 * s + tapoff;
        int kd = tap / 9;
        int t2 = tap - kd * 9;
        int kh = t2 / 3;
        int kw = t2 - kh * 3;
        int di = z + kd - 1, hi = y + kh - 1, wi = xx + kw - 1;
        bool ok = (tap < 27) && ((unsigned)di < 48u) && ((unsigned)hi < 48u) &&
                  ((unsigned)wi < 48u);
        uint4 v = make_uint4(0u, 0u, 0u, 0u);
        if (ok) {
            size_t off = ((size_t)(n * SP + (di * 2304 + hi * 48 + wi))) * 16 + half * 8;
            v = *(const uint4*)(xT + off);
        }
        return v;
    };

    f32x4 acc[6];
    #pragma unroll
    for (int t = 0; t < 6; ++t) acc[t] = (f32x4){0.f, 0.f, 0.f, 0.f};

    uint4 v = stage_load(0);
    for (int s = 0; s < 14; ++s) {
        __syncthreads();
        *(uint4*)&Alds[tid * 8] = v;
        __syncthreads();
        if (s < 13) v = stage_load(s + 1);        // prefetch overlaps MFMA
        f16x8 a = *(const f16x8*)&Alds[(((lane >> 4) * 64) + (wid * 16) + (lane & 15)) * 8];
        const f16x8* bp = (const f16x8*)Bf + (size_t)(s * 6) * 64 + lane;
        #pragma unroll
        for (int nt = 0; nt < 6; ++nt) {
            f16x8 b = bp[nt * 64];
            acc[nt] = __builtin_amdgcn_mfma_f32_16x16x32_f16(a, b, acc[nt], 0, 0, 0);
        }
    }

    // epilogue: bias + f16 into LDS [row][g] (stride 104), then contiguous out
    const int mrow = wid * 16 + ((lane >> 4) << 2);
    #pragma unroll
    for (int nt = 0; nt < 6; ++nt) {
        int g = nt * 16 + (lane & 15);
        float bia = (g < 81) ? ob[g] : 0.f;
        #pragma unroll
        for (int r = 0; r < 4; ++r)
            Tl[(mrow + r) * 104 + g] = f2h(acc[nt][r] + bia);
    }
    __syncthreads();
    unsigned short* dst = offs + (size_t)bid * (64 * OST);
    #pragma unroll
    for (int k = 0; k < 3; ++k) {
        int idx = k * 256 + tid;                  // 0..767 uint4-chunks
        int row = idx / 12;
        int col = (idx - row * 12) * 8;
        uint4 vv = *(const uint4*)&Tl[row * 104 + col];
        *(uint4*)(dst + row * OST + col) = vv;
    }
}

// ---------- Kernel 2: full-K-per-wave fused sampling, packed-f16 interp ------
// 512 threads = 8 waves x 16 points = 128 points/block (1728 blocks exact).
// Per k-step each lane does one half-sample (p=lane&15, tap=2s+(lane>>5),
// chh=(lane>>4)&1) + 2 MFMAs. Interp accumulates in PACKED f16 (__hfma2 ->
// v_pk_fma_f16, 2 ch/op); the accumulator IS the A-fragment (no final cvt).
// x stays 16-bit (R13 lesson: f32 copy blows the 4MB XCD L2).
// PLATEAU NOTE (R11-R19): eight structural variants all land 108-114us;
// binder is the L1/TA scattered-gather rate (95.6M divergent 16B gathers),
// not VALU (41%), not occupancy, not LDS, not HBM. Manual vmcnt pipelining
// (R18/R19) crashed/hung - compiler-tracked loads are the stable form.
// REGISTER-CAP HISTORY (do not tighten): cap<=64 on this sampler spills
// (R5: FETCH x7, R9: WRITE x5). (512,4) -> cap non-binding.
__global__ __launch_bounds__(512, 4)
void deform_fused(const unsigned short* __restrict__ xT,
                  const unsigned short* __restrict__ Wf,
                  const unsigned short* __restrict__ offs,
                  float* __restrict__ out) {
    __shared__ unsigned short OLDS[128 * OLROW];  // 25.6KB offsets

    const int tid  = threadIdx.x;
    const int lane = tid & 63;
    const int wv   = tid >> 6;                    // wave 0..7
    const int pl   = lane & 15;                   // point-local (A-frag row)
    const int chh  = (lane >> 4) & 1;             // channel half
    const int tl   = lane >> 5;                   // tap-local in k-step
    // XCD-aware chunked swizzle: 1728 = 8 x 216
    const int bid  = (blockIdx.x & 7) * 216 + (blockIdx.x >> 3);
    const int n    = (bid >= 864) ? 1 : 0;
    const int sp0  = bid * 128 - n * SP;

    // ---- phase 0: coalesced offset preload (128 rows x 96 ush = 1536 uint4) -
    #pragma unroll
    for (int k = 0; k < 3; ++k) {
        int idx = k * 512 + tid;
        int row = idx / 12;
        int col = (idx - row * 12) * 8;
        uint4 v = *(const uint4*)(offs + ((size_t)(n * SP + sp0 + row)) * OST + col);
        *(uint4*)&OLDS[row * OLROW + col] = v;
    }
    __syncthreads();

    const uint4* xq4 = (const uint4*)(xT + (size_t)n * SP * 16);

    const int p  = wv * 16 + pl;                  // point 0..127
    const int sp = sp0 + p;
    const int z  = sp / 2304;
    const int rm = sp - z * 2304;
    const int y  = rm / 48;
    const int xx = rm - y * 48;

    f32x4 acc0 = (f32x4){0.f, 0.f, 0.f, 0.f};
    f32x4 acc1 = (f32x4){0.f, 0.f, 0.f, 0.f};

    #pragma unroll 2
    for (int s = 0; s < 14; ++s) {
        const int tap = 2 * s + tl;               // 0..27 (27 = zero pad)
        uint4 au = make_uint4(0u, 0u, 0u, 0u);
        if (tap < 27) {
            const int kd = tap / 9;
            const int t2 = tap - kd * 9;
            const int kh = t2 / 3;
            const int kw = t2 - kh * 3;
            float pd = (float)(z + kd - 1)  + h2f(OLDS[p * OLROW + tap]);
            float ph = (float)(y + kh - 1)  + h2f(OLDS[p * OLROW + 27 + tap]);
            float pw = (float)(xx + kw - 1) + h2f(OLDS[p * OLROW + 54 + tap]);
            float df = floorf(pd), hf = floorf(ph), wf = floorf(pw);
            float fd = pd - df, fh = ph - hf, fw = pw - wf;
            int d0 = (int)df, h0 = (int)hf, w0 = (int)wf;
            float wd0 = ((unsigned)d0       < 48u) ? (1.f - fd) : 0.f;
            float wd1 = ((unsigned)(d0 + 1) < 48u) ? fd : 0.f;
            float wh0 = ((unsigned)h0       < 48u) ? (1.f - fh) : 0.f;
            float wh1 = ((unsigned)(h0 + 1) < 48u) ? fh : 0.f;
            float ww0 = ((unsigned)w0       < 48u) ? (1.f - fw) : 0.f;
            float ww1 = ((unsigned)(w0 + 1) < 48u) ? fw : 0.f;
            int dc0 = min(max(d0,     0), 47) * 2304;
            int dc1 = min(max(d0 + 1, 0), 47) * 2304;
            int hc0 = min(max(h0,     0), 47) * 48;
            int hc1 = min(max(h0 + 1, 0), 47) * 48;
            int wc0 = min(max(w0,     0), 47);
            int wc1 = min(max(w0 + 1, 0), 47);

            float wdh[4] = {wd0 * wh0, wd0 * wh1, wd1 * wh0, wd1 * wh1};
            int   rdh[4] = {dc0 + hc0, dc0 + hc1, dc1 + hc0, dc1 + hc1};

            // 8 corner gathers in flight (this lane's channel half only)
            uint4 cv[8];
            float cw[8];
            #pragma unroll
            for (int jj = 0; jj < 8; ++jj) {
                int dh = jj >> 1;
                int ws = jj & 1;
                int idx = rdh[dh] + (ws ? wc1 : wc0);
                cv[jj] = xq4[(size_t)idx * 2 + chh];
                cw[jj] = wdh[dh] * (ws ? ww1 : ww0);
            }

            // packed-f16 interp: acc IS the A-fragment (no final cvt)
            const __half2 z2 = __builtin_bit_cast(__half2, (unsigned int)0);
            __half2 s2[4] = {z2, z2, z2, z2};
            #pragma unroll
            for (int jj = 0; jj < 8; ++jj) {
                unsigned int wp;
                asm("v_cvt_pkrtz_f16_f32 %0, %1, %2" : "=v"(wp) : "v"(cw[jj]), "v"(cw[jj]));
                __half2 wh = __builtin_bit_cast(__half2, wp);
                unsigned int uu[4] = {cv[jj].x, cv[jj].y, cv[jj].z, cv[jj].w};
                #pragma unroll
                for (int q = 0; q < 4; ++q)
                    s2[q] = __hfma2(__builtin_bit_cast(__half2, uu[q]), wh, s2[q]);
            }
            au = make_uint4(__builtin_bit_cast(unsigned int, s2[0]),
                            __builtin_bit_cast(unsigned int, s2[1]),
                            __builtin_bit_cast(unsigned int, s2[2]),
                            __builtin_bit_cast(unsigned int, s2[3]));
        }
        f16x8 a = __builtin_bit_cast(f16x8, au);
        const f16x8* bp = (const f16x8*)Wf + (size_t)(s * 2) * 64 + lane;
        acc0 = __builtin_amdgcn_mfma_f32_16x16x32_f16(a, bp[0],  acc0, 0, 0, 0);
        acc1 = __builtin_amdgcn_mfma_f32_16x16x32_f16(a, bp[64], acc1, 0, 0, 0);
    }

    // ---- epilogue: direct float4 stores (rows 4q..4q+3 = consecutive sp) ----
    {
        const int o   = lane & 15;
        const int row = (lane >> 4) << 2;         // 0,4,8,12
        float* op0 = out + ((size_t)(n * O_OUT + o))      * SP + sp0 + wv * 16 + row;
        float* op1 = out + ((size_t)(n * O_OUT + 16 + o)) * SP + sp0 + wv * 16 + row;
        *(float4*)op0 = make_float4(acc0[0], acc0[1], acc0[2], acc0[3]);
        *(float4*)op1 = make_float4(acc1[0], acc1[1], acc1[2], acc1[3]);
    }
}

// -----------------------------------------------------------------------------
extern "C" void kernel_launch(void* const* d_in, const int* in_sizes, int n_in,
                              void* d_out, int out_size, void* d_ws, size_t ws_size,
                              hipStream_t stream) {
    (void)in_sizes; (void)n_in; (void)out_size; (void)ws_size;
    const float* x      = (const float*)d_in[0];
    const float* weight = (const float*)d_in[1];
    const float* ow     = (const float*)d_in[2];
    const float* ob     = (const float*)d_in[3];
    float* out = (float*)d_out;

    unsigned short* offs_b = (unsigned short*)d_ws;            // 2*SP*96 f16 = 42.5MB
    unsigned short* xT     = offs_b + (size_t)2 * SP * OST;    // 2*SP*16 f16 = 7.1MB
    unsigned short* Bf     = xT + (size_t)2 * SP * 16;         // 43008 f16
    unsigned short* Wf     = Bf + 43008;                       // 14336 f16

    prep_xT<<<864, 256, 0, stream>>>(x, xT);
    prep_bfrag<<<168, 256, 0, stream>>>(ow, Bf);
    prep_wfrag<<<56, 256, 0, stream>>>(weight, Wf);
    offs_conv_mfma<<<3456, 256, 0, stream>>>(xT, Bf, ob, offs_b);
    deform_fused<<<1728, 512, 0, stream>>>(xT, Wf, offs_b, out);
}